// Round 6
// baseline (2216.614 us; speedup 1.0000x reference)
//
#include <hip/hip_runtime.h>

// ---------- helpers ----------
__device__ __forceinline__ unsigned short f2b(float f) {
    unsigned int u = __builtin_bit_cast(unsigned int, f);
    unsigned int r = (u + 0x7FFFu + ((u >> 16) & 1u)) >> 16;  // RNE
    return (unsigned short)r;
}
__device__ __forceinline__ float b2f(unsigned short s) {
    unsigned int u = ((unsigned int)s) << 16;
    return __builtin_bit_cast(float, u);
}
__device__ __forceinline__ void st_agent_f32(float* p, float v) {
    __hip_atomic_store((unsigned int*)p, __builtin_bit_cast(unsigned int, v),
                       __ATOMIC_RELAXED, __HIP_MEMORY_SCOPE_AGENT);
}
__device__ __forceinline__ float ld_agent_f32(const float* p) {
    unsigned int u = __hip_atomic_load((const unsigned int*)p,
                                       __ATOMIC_RELAXED, __HIP_MEMORY_SCOPE_AGENT);
    return __builtin_bit_cast(float, u);
}

typedef __attribute__((ext_vector_type(8))) short short8;
typedef __attribute__((ext_vector_type(4))) float float4v;

#define GLD16(g, l) __builtin_amdgcn_global_load_lds(                          \
    (const __attribute__((address_space(1))) unsigned int*)(g),                \
    (__attribute__((address_space(3))) unsigned int*)(l), 16, 0, 0)

#define WAIT_VM12() __builtin_amdgcn_s_waitcnt(0x0F7C)  // vmcnt(12)
#define WAIT_VM0()  __builtin_amdgcn_s_waitcnt(0x0F70)  // vmcnt(0)

// L=16384, D_IN=512, D_H=1024, D_OUT=512
#define SEQLEN 16384
#define NCHUNK 256
#define TCHUNK 64
#define LDH 2560   // Hcat row stride (cols: [0,2048)=Bu/h, [2048,2560)=x_bf16)

// ---------- merged prep: xcast + prep_B + prep_CW + flag zeroing ----------
__global__ void prep_all(const float* __restrict__ x,
                         const float* __restrict__ B_re, const float* __restrict__ B_im,
                         const float* __restrict__ gamma,
                         const float* __restrict__ C_re, const float* __restrict__ C_im,
                         const float* __restrict__ Dm,
                         unsigned short* __restrict__ Hcat,
                         unsigned short* __restrict__ Bcat,
                         unsigned short* __restrict__ CW,
                         int* __restrict__ flags) {
    int b = blockIdx.x;
    if (b < 8192) {
        int id = b * 256 + threadIdx.x;            // one per 4 elements of [16384 x 512]
        int t = id >> 7;
        int k4 = (id & 127) << 2;
        float4 v = *(const float4*)(x + (long)t * 512 + k4);
        ushort4 o;
        o.x = f2b(v.x); o.y = f2b(v.y); o.z = f2b(v.z); o.w = f2b(v.w);
        *(ushort4*)(Hcat + (long)t * LDH + 2048 + k4) = o;
    } else if (b < 9216) {
        int id = (b - 8192) * 256 + threadIdx.x;   // one per 4 elements of [2048 x 512]
        int n = id >> 7;
        int k4 = (id & 127) << 2;
        const float* src = (n < 1024) ? (B_re + (long)n * 512) : (B_im + (long)(n - 1024) * 512);
        float g = expf(gamma[n & 1023]);
        float4 v = *(const float4*)(src + k4);
        ushort4 o;
        o.x = f2b(v.x * g); o.y = f2b(v.y * g); o.z = f2b(v.z * g); o.w = f2b(v.w * g);
        *(ushort4*)(Bcat + (long)n * 512 + k4) = o;
    } else {
        if (b == 9216) flags[threadIdx.x] = 0;     // zero NCHUNK=256 flags (stream-ordered before scan)
        int id = (b - 9216) * 256 + threadIdx.x;   // one per 4 elements of [512 x 2560]
        int o = id / 640;
        int j4 = (id - o * 640) << 2;
        float4 v; float sgn = 1.0f;
        if (j4 < 1024) {
            v = *(const float4*)(C_re + (long)o * 1024 + j4);
        } else if (j4 < 2048) {
            v = *(const float4*)(C_im + (long)o * 1024 + (j4 - 1024));
            sgn = -1.0f;
        } else {
            v = *(const float4*)(Dm + (long)o * 512 + (j4 - 2048));
        }
        ushort4 w;
        w.x = f2b(v.x * sgn); w.y = f2b(v.y * sgn); w.z = f2b(v.z * sgn); w.w = f2b(v.w * sgn);
        *(ushort4*)(CW + (long)o * 2560 + j4) = w;
    }
}

// ---------- GEMM1: 128x128 tile, BK=32, bf16 out, LDS-restaged epilogue (R2 best) ----------
__launch_bounds__(256)
__global__ void g1_bu_gemm(const unsigned short* __restrict__ A, int lda,
                           const unsigned short* __restrict__ B, int ldb,
                           unsigned short* __restrict__ Cout, int ldc, int Ktot,
                           int nbx_shift, int nby_d8) {
    __shared__ unsigned short smem[8192] __attribute__((aligned(16)));
    unsigned short* As = smem;
    unsigned short* Bs = smem + 4096;
    const int tid = threadIdx.x;
    const int wave = tid >> 6;
    const int lane = tid & 63;

    const int bid = blockIdx.x;
    const int xcd = bid & 7;
    const int g = bid >> 3;
    const int bx = g & ((1 << nbx_shift) - 1);
    const int by = xcd * nby_d8 + (g >> nbx_shift);
    const long m0 = (long)by * 128;
    const long n0 = (long)bx * 128;

    const int wm = (wave >> 1) * 64;
    const int wn = (wave & 1) * 64;

    const int s1 = wave * 64 + lane;
    const int r1 = s1 >> 2, c1 = (s1 & 3) * 8;
    const int s2 = s1 + 256;
    const int r2 = s2 >> 2, c2 = (s2 & 3) * 8;
    const unsigned short* Arow1 = A + (m0 + r1) * lda + c1;
    const unsigned short* Arow2 = A + (m0 + r2) * lda + c2;
    const unsigned short* Brow1 = B + (n0 + r1) * ldb + c1;
    const unsigned short* Brow2 = B + (n0 + r2) * ldb + c2;
    char* AsB1 = (char*)As + wave * 1024;
    char* AsB2 = (char*)As + 4096 + wave * 1024;
    char* BsB1 = (char*)Bs + wave * 1024;
    char* BsB2 = (char*)Bs + 4096 + wave * 1024;

    const int fr = lane & 15;
    const int fk = (lane >> 4) * 8;

    float4v acc[4][4] = {};

    for (int k0 = 0; k0 < Ktot; k0 += 32) {
        GLD16(Arow1 + k0, AsB1);
        GLD16(Arow2 + k0, AsB2);
        GLD16(Brow1 + k0, BsB1);
        GLD16(Brow2 + k0, BsB2);
        __syncthreads();
        short8 af[4], bfr[4];
#pragma unroll
        for (int i = 0; i < 4; i++) {
            af[i]  = *(const short8*)(As + (wm + i * 16 + fr) * 32 + fk);
            bfr[i] = *(const short8*)(Bs + (wn + i * 16 + fr) * 32 + fk);
        }
#pragma unroll
        for (int mi = 0; mi < 4; mi++)
#pragma unroll
            for (int ni = 0; ni < 4; ni++)
                acc[mi][ni] = __builtin_amdgcn_mfma_f32_16x16x32_bf16(af[mi], bfr[ni], acc[mi][ni], 0, 0, 0);
        __syncthreads();
    }

    // epilogue: restage each 32x128 row-slab through LDS, store ushort8
    const int er = (lane >> 4) * 4;
    const int ec = lane & 15;
    const int rowg = wm >> 6;
#pragma unroll
    for (int mi = 0; mi < 4; mi++) {
        __syncthreads();
#pragma unroll
        for (int ni = 0; ni < 4; ni++)
#pragma unroll
            for (int r = 0; r < 4; r++)
                smem[(rowg * 16 + er + r) * 136 + wn + ni * 16 + ec] = f2b(acc[mi][ni][r]);
        __syncthreads();
#pragma unroll
        for (int h = 0; h < 2; h++) {
            int j = h * 256 + tid;
            int rp = j >> 4;
            int cp = (j & 15) * 8;
            short8 v = *(const short8*)(smem + rp * 136 + cp);
            long grow = m0 + (rp >> 4) * 64 + mi * 16 + (rp & 15);
            *(short8*)(Cout + grow * ldc + n0 + cp) = v;
        }
    }
}

// ---------- GEMM2: single-wave 64x128 tile, BK=32, LDS dbuf + vmcnt(12) (R4 best) ----------
__launch_bounds__(64, 2)
__global__ void g2_out_gemm(const unsigned short* __restrict__ A, int lda,
                            const unsigned short* __restrict__ B, int ldb,
                            float* __restrict__ Cout, int ldc, int Ktot,
                            int nbx_shift) {
    __shared__ unsigned short sm[2][6144] __attribute__((aligned(16)));
    const int lane = threadIdx.x;

    const int bid = blockIdx.x;
    const int xcd = bid & 7;
    const int g = bid >> 3;
    const int bx = g & ((1 << nbx_shift) - 1);
    const int by = xcd * 32 + (g >> nbx_shift);
    const long m0 = (long)by * 64;
    const long n0 = (long)bx * 128;

    const unsigned short* Ag = A + (m0 + (lane >> 2)) * lda + (lane & 3) * 8;
    const unsigned short* Bg = B + (n0 + (lane >> 2)) * ldb + (lane & 3) * 8;

    const int fr = lane & 15;
    const int fk = (lane >> 4) * 8;

    float4v acc[4][8] = {};

    auto stage = [&](int b, int k0) {
#pragma unroll
        for (int i = 0; i < 4; i++)
            GLD16(Ag + (long)i * 16 * lda + k0, &sm[b][i * 512]);
#pragma unroll
        for (int j = 0; j < 8; j++)
            GLD16(Bg + (long)j * 16 * ldb + k0, &sm[b][2048 + j * 512]);
    };
    auto compute = [&](int b) {
        short8 af[4], bf8[8];
#pragma unroll
        for (int i = 0; i < 4; i++)
            af[i] = *(const short8*)(&sm[b][(i * 16 + fr) * 32 + fk]);
#pragma unroll
        for (int j = 0; j < 8; j++)
            bf8[j] = *(const short8*)(&sm[b][2048 + (j * 16 + fr) * 32 + fk]);
#pragma unroll
        for (int mi = 0; mi < 4; mi++)
#pragma unroll
            for (int ni = 0; ni < 8; ni++)
                acc[mi][ni] = __builtin_amdgcn_mfma_f32_16x16x32_bf16(af[mi], bf8[ni], acc[mi][ni], 0, 0, 0);
    };

    stage(0, 0);
    int buf = 0;
    int k0 = 0;
    for (; k0 + 32 < Ktot; k0 += 32) {
        stage(buf ^ 1, k0 + 32);
        WAIT_VM12();
        compute(buf);
        buf ^= 1;
    }
    WAIT_VM0();
    compute(buf);

    const int er = (lane >> 4) * 4;
    const int ec = lane & 15;
#pragma unroll
    for (int mi = 0; mi < 4; mi++) {
#pragma unroll
        for (int r = 0; r < 4; r++) {
            long grow = m0 + mi * 16 + er + r;
#pragma unroll
            for (int ni = 0; ni < 8; ni++)
                Cout[grow * ldc + n0 + ni * 16 + ec] = acc[mi][ni][r];
        }
    }
}

// ---------- single-pass scan: local ends + decoupled aggregate look-back + apply ----------
// 256 blocks (chunk c = 64 timesteps) x 512 threads (2 complex ch each).
// All 256 blocks co-resident (1/CU, tiny LDS/VGPR) => flag polling cannot deadlock.
__launch_bounds__(512)
__global__ void scan_onepass(unsigned short* __restrict__ Hcat,
                             const float* __restrict__ lamb,
                             float* __restrict__ E,      // [NCHUNK][2048]
                             int* __restrict__ flags) {  // [NCHUNK], zeroed by prep_all
    const int c = blockIdx.x;
    const int ch = threadIdx.x << 1;   // 2 complex channels
    float lre[2], lim[2], t64re[2], t64im[2];
#pragma unroll
    for (int i = 0; i < 2; i++) {
        float nu = expf(-expf(lamb[ch + i]));
        float th = expf(lamb[1024 + ch + i]);
        lre[i] = nu * cosf(th);
        lim[i] = nu * sinf(th);
        double dnu = exp(-exp((double)lamb[ch + i]));
        double dth = exp((double)lamb[1024 + ch + i]);
        double lr = dnu * cos(dth), li = dnu * sin(dth);
#pragma unroll
        for (int s = 0; s < 6; s++) {  // lambda^64
            double rr = lr * lr - li * li;
            double ii = 2.0 * lr * li;
            lr = rr; li = ii;
        }
        t64re[i] = (float)lr; t64im[i] = (float)li;
    }

    unsigned short* base = Hcat + (long)c * TCHUNK * LDH + ch;

    // phase 1: local end state (zero seed)
    float hr[2] = {0, 0}, hi[2] = {0, 0};
#pragma unroll 4
    for (int t = 0; t < TCHUNK; t++) {
        ushort2 br = *(const ushort2*)(base + (long)t * LDH);
        ushort2 bi = *(const ushort2*)(base + (long)t * LDH + 1024);
        float brf[2] = {b2f(br.x), b2f(br.y)};
        float bif[2] = {b2f(bi.x), b2f(bi.y)};
#pragma unroll
        for (int i = 0; i < 2; i++) {
            float nr = fmaf(lre[i], hr[i], fmaf(-lim[i], hi[i], brf[i]));
            float ni = fmaf(lre[i], hi[i], fmaf(lim[i], hr[i], bif[i]));
            hr[i] = nr; hi[i] = ni;
        }
    }
    // publish aggregate E_c (agent-scope stores dodge stale per-XCD L2 across replays)
    float* Ec = E + (long)c * 2048 + ch;
    st_agent_f32(Ec + 0, hr[0]);
    st_agent_f32(Ec + 1, hr[1]);
    st_agent_f32(Ec + 1024, hi[0]);
    st_agent_f32(Ec + 1025, hi[1]);
    __threadfence();
    __syncthreads();
    if (threadIdx.x == 0)
        __hip_atomic_store(flags + c, 1, __ATOMIC_RELEASE, __HIP_MEMORY_SCOPE_AGENT);

    // look-back: carry = sum_{j<c} lambda^(64*(c-1-j)) * E_j  (Horner ascending; depth-1 dep)
    float cre[2] = {0, 0}, cim[2] = {0, 0};
    for (int j = 0; j < c; j++) {
        while (__hip_atomic_load(flags + j, __ATOMIC_ACQUIRE, __HIP_MEMORY_SCOPE_AGENT) != 1) {}
        const float* Ej = E + (long)j * 2048 + ch;
        float er0 = ld_agent_f32(Ej + 0),    er1 = ld_agent_f32(Ej + 1);
        float ei0 = ld_agent_f32(Ej + 1024), ei1 = ld_agent_f32(Ej + 1025);
        float nr0 = fmaf(t64re[0], cre[0], fmaf(-t64im[0], cim[0], er0));
        float ni0 = fmaf(t64re[0], cim[0], fmaf(t64im[0], cre[0], ei0));
        float nr1 = fmaf(t64re[1], cre[1], fmaf(-t64im[1], cim[1], er1));
        float ni1 = fmaf(t64re[1], cim[1], fmaf(t64im[1], cre[1], ei1));
        cre[0] = nr0; cim[0] = ni0; cre[1] = nr1; cim[1] = ni1;
    }

    // phase 3: re-scan seeded with carry, write h bf16 in place
    hr[0] = cre[0]; hr[1] = cre[1]; hi[0] = cim[0]; hi[1] = cim[1];
#pragma unroll 4
    for (int t = 0; t < TCHUNK; t++) {
        ushort2 br = *(const ushort2*)(base + (long)t * LDH);
        ushort2 bi = *(const ushort2*)(base + (long)t * LDH + 1024);
        float brf[2] = {b2f(br.x), b2f(br.y)};
        float bif[2] = {b2f(bi.x), b2f(bi.y)};
#pragma unroll
        for (int i = 0; i < 2; i++) {
            float nr = fmaf(lre[i], hr[i], fmaf(-lim[i], hi[i], brf[i]));
            float ni = fmaf(lre[i], hi[i], fmaf(lim[i], hr[i], bif[i]));
            hr[i] = nr; hi[i] = ni;
        }
        ushort2 orv, oiv;
        orv.x = f2b(hr[0]); orv.y = f2b(hr[1]);
        oiv.x = f2b(hi[0]); oiv.y = f2b(hi[1]);
        *(ushort2*)(base + (long)t * LDH) = orv;
        *(ushort2*)(base + (long)t * LDH + 1024) = oiv;
    }
}

// ---------- launch ----------
extern "C" void kernel_launch(void* const* d_in, const int* in_sizes, int n_in,
                              void* d_out, int out_size, void* d_ws, size_t ws_size,
                              hipStream_t stream) {
    const float* x     = (const float*)d_in[0];  // [16384, 512]
    const float* lamb  = (const float*)d_in[1];  // [2, 1024]
    const float* gamma = (const float*)d_in[2];  // [1024]
    const float* B_re  = (const float*)d_in[3];  // [1024, 512]
    const float* B_im  = (const float*)d_in[4];
    const float* C_re  = (const float*)d_in[5];  // [512, 1024]
    const float* C_im  = (const float*)d_in[6];
    const float* Dm    = (const float*)d_in[7];  // [512, 512]

    char* ws = (char*)d_ws;
    unsigned short* Hcat = (unsigned short*)ws;                      // 16384*2560*2 = 83886080
    float* E    = (float*)(ws + 83886080);                           // 256*2048*4 = 2097152
    int* flags  = (int*)(ws + 83886080 + 2097152);                   // 256*4
    unsigned short* Bcat = (unsigned short*)(ws + 83886080 + 2097152 + 4096);   // 2048*512*2
    unsigned short* CW   = Bcat + (long)2048 * 512;                  // 512*2560*2

    prep_all<<<10496, 256, 0, stream>>>(x, B_re, B_im, gamma, C_re, C_im, Dm,
                                        Hcat, Bcat, CW, flags);
    // Bu = x_bf16 @ Bcat^T -> Hcat cols [0,2048).  grid 16x128 = 2048 blocks, swizzled.
    g1_bu_gemm<<<2048, 256, 0, stream>>>(Hcat + 2048, LDH, Bcat, 512, Hcat, LDH, 512,
                                         /*nbx_shift=*/4, /*nby_d8=*/16);
    // single-pass scan over 256 chunks of 64 timesteps
    scan_onepass<<<NCHUNK, 512, 0, stream>>>(Hcat, lamb, E, flags);
    // y = Hcat @ CW^T -> d_out f32.  grid 256(by) x 4(bx) = 1024 single-wave blocks.
    g2_out_gemm<<<1024, 64, 0, stream>>>(Hcat, LDH, CW, 2560, (float*)d_out, 512, 2560,
                                         /*nbx_shift=*/2);
}

// Round 7
// 289.537 us; speedup vs baseline: 7.6557x; 7.6557x over previous
//
#include <hip/hip_runtime.h>

// ---------- helpers ----------
__device__ __forceinline__ unsigned short f2b(float f) {
    unsigned int u = __builtin_bit_cast(unsigned int, f);
    unsigned int r = (u + 0x7FFFu + ((u >> 16) & 1u)) >> 16;  // RNE
    return (unsigned short)r;
}
__device__ __forceinline__ float b2f(unsigned short s) {
    unsigned int u = ((unsigned int)s) << 16;
    return __builtin_bit_cast(float, u);
}

typedef __attribute__((ext_vector_type(8))) short short8;
typedef __attribute__((ext_vector_type(4))) float float4v;

#define GLD16(g, l) __builtin_amdgcn_global_load_lds(                          \
    (const __attribute__((address_space(1))) unsigned int*)(g),                \
    (__attribute__((address_space(3))) unsigned int*)(l), 16, 0, 0)

#define WAIT_VM12() __builtin_amdgcn_s_waitcnt(0x0F7C)  // vmcnt(12)
#define WAIT_VM0()  __builtin_amdgcn_s_waitcnt(0x0F70)  // vmcnt(0)

// L=16384, D_IN=512, D_H=1024, D_OUT=512
#define SEQLEN 16384
#define NCHUNK 256
#define TCHUNK 64
#define LDH 2560   // Hcat row stride (cols: [0,2048)=Bu/h, [2048,2560)=x_bf16)

// ---------- merged prep: xcast + prep_B + prep_CW + lambda table ----------
__global__ void prep_all(const float* __restrict__ x,
                         const float* __restrict__ B_re, const float* __restrict__ B_im,
                         const float* __restrict__ gamma,
                         const float* __restrict__ C_re, const float* __restrict__ C_im,
                         const float* __restrict__ Dm, const float* __restrict__ lamb,
                         unsigned short* __restrict__ Hcat,
                         unsigned short* __restrict__ Bcat,
                         unsigned short* __restrict__ CW,
                         float2* __restrict__ Ltab) {
    int b = blockIdx.x;
    if (b < 8192) {
        int id = b * 256 + threadIdx.x;            // one per 4 elements of [16384 x 512]
        int t = id >> 7;
        int k4 = (id & 127) << 2;
        float4 v = *(const float4*)(x + (long)t * 512 + k4);
        ushort4 o;
        o.x = f2b(v.x); o.y = f2b(v.y); o.z = f2b(v.z); o.w = f2b(v.w);
        *(ushort4*)(Hcat + (long)t * LDH + 2048 + k4) = o;
    } else if (b < 9216) {
        int id = (b - 8192) * 256 + threadIdx.x;   // one per 4 elements of [2048 x 512]
        int n = id >> 7;
        int k4 = (id & 127) << 2;
        const float* src = (n < 1024) ? (B_re + (long)n * 512) : (B_im + (long)(n - 1024) * 512);
        float g = expf(gamma[n & 1023]);
        float4 v = *(const float4*)(src + k4);
        ushort4 o;
        o.x = f2b(v.x * g); o.y = f2b(v.y * g); o.z = f2b(v.z * g); o.w = f2b(v.w * g);
        *(ushort4*)(Bcat + (long)n * 512 + k4) = o;
    } else {
        if (b == 9216) {                           // lambda table (1024 ch / 256 thr)
#pragma unroll
            for (int i = 0; i < 4; i++) {
                int ch = threadIdx.x * 4 + i;
                float nu = expf(-expf(lamb[ch]));
                float th = expf(lamb[1024 + ch]);
                float2 l; l.x = nu * cosf(th); l.y = nu * sinf(th);
                Ltab[ch] = l;
            }
        }
        int id = (b - 9216) * 256 + threadIdx.x;   // one per 4 elements of [512 x 2560]
        int o = id / 640;
        int j4 = (id - o * 640) << 2;
        float4 v; float sgn = 1.0f;
        if (j4 < 1024) {
            v = *(const float4*)(C_re + (long)o * 1024 + j4);
        } else if (j4 < 2048) {
            v = *(const float4*)(C_im + (long)o * 1024 + (j4 - 1024));
            sgn = -1.0f;
        } else {
            v = *(const float4*)(Dm + (long)o * 512 + (j4 - 2048));
        }
        ushort4 w;
        w.x = f2b(v.x * sgn); w.y = f2b(v.y * sgn); w.z = f2b(v.z * sgn); w.w = f2b(v.w * sgn);
        *(ushort4*)(CW + (long)o * 2560 + j4) = w;
    }
}

// ---------- GEMM1: 128x128 tile, BK=32, bf16 out + chunk-end-state fold ----------
// Each wave's 64x64 acc sub-tile = (one 64-row chunk) x (64 Bu-cols).
// E_c[col] = sum_t lam^(63-t) * Bu[64c+t][col], computed from fp32 acc:
//   63 - (16mi + 4q + r) = 16(3-mi) + 4(3-q) + (3-r)
// Re-cols (n<1024) -> P1 (complex), Im-cols -> P2;  apply_scan combines E = P1 + i*P2.
__launch_bounds__(256)
__global__ void g1_bu_gemm(const unsigned short* __restrict__ A, int lda,
                           const unsigned short* __restrict__ B, int ldb,
                           unsigned short* __restrict__ Cout, int ldc, int Ktot,
                           const float2* __restrict__ Ltab,
                           float2* __restrict__ P1, float2* __restrict__ P2) {
    __shared__ unsigned short smem[8192] __attribute__((aligned(16)));
    unsigned short* As = smem;
    unsigned short* Bs = smem + 4096;
    const int tid = threadIdx.x;
    const int wave = tid >> 6;
    const int lane = tid & 63;

    const int bid = blockIdx.x;
    const int xcd = bid & 7;
    const int g = bid >> 3;
    const int bx = g & 15;               // 16 n-tiles
    const int by = xcd * 16 + (g >> 4);  // 128 m-tiles
    const long m0 = (long)by * 128;
    const long n0 = (long)bx * 128;

    const int wm = (wave >> 1) * 64;
    const int wn = (wave & 1) * 64;

    const int s1 = wave * 64 + lane;
    const int r1 = s1 >> 2, c1 = (s1 & 3) * 8;
    const int s2 = s1 + 256;
    const int r2 = s2 >> 2, c2 = (s2 & 3) * 8;
    const unsigned short* Arow1 = A + (m0 + r1) * lda + c1;
    const unsigned short* Arow2 = A + (m0 + r2) * lda + c2;
    const unsigned short* Brow1 = B + (n0 + r1) * ldb + c1;
    const unsigned short* Brow2 = B + (n0 + r2) * ldb + c2;
    char* AsB1 = (char*)As + wave * 1024;
    char* AsB2 = (char*)As + 4096 + wave * 1024;
    char* BsB1 = (char*)Bs + wave * 1024;
    char* BsB2 = (char*)Bs + 4096 + wave * 1024;

    const int fr = lane & 15;
    const int fk = (lane >> 4) * 8;

    float4v acc[4][4] = {};

    for (int k0 = 0; k0 < Ktot; k0 += 32) {
        GLD16(Arow1 + k0, AsB1);
        GLD16(Arow2 + k0, AsB2);
        GLD16(Brow1 + k0, BsB1);
        GLD16(Brow2 + k0, BsB2);
        __syncthreads();
        short8 af[4], bfr[4];
#pragma unroll
        for (int i = 0; i < 4; i++) {
            af[i]  = *(const short8*)(As + (wm + i * 16 + fr) * 32 + fk);
            bfr[i] = *(const short8*)(Bs + (wn + i * 16 + fr) * 32 + fk);
        }
#pragma unroll
        for (int mi = 0; mi < 4; mi++)
#pragma unroll
            for (int ni = 0; ni < 4; ni++)
                acc[mi][ni] = __builtin_amdgcn_mfma_f32_16x16x32_bf16(af[mi], bfr[ni], acc[mi][ni], 0, 0, 0);
        __syncthreads();
    }

    // ---- E-fold: chunk c = 2*by + (wm>>6); C/D layout col=lane&15, row=q*4+r (+16mi) ----
    const int q = lane >> 4;
    const int ec = lane & 15;
    const int c_chunk = 2 * by + (wm >> 6);
#pragma unroll
    for (int ni = 0; ni < 4; ni++) {
        int ncol = (int)n0 + wn + ni * 16 + ec;
        float2 lam = Ltab[ncol & 1023];
        float lr = lam.x, li = lam.y;
        float l2r = lr*lr - li*li,     l2i = 2.f*lr*li;
        float l3r = l2r*lr - l2i*li,   l3i = l2r*li + l2i*lr;
        float l4r = l2r*l2r - l2i*l2i, l4i = 2.f*l2r*l2i;
        float l8r = l4r*l4r - l4i*l4i, l8i = 2.f*l4r*l4i;
        float l12r = l8r*l4r - l8i*l4i,    l12i = l8r*l4i + l8i*l4r;
        float l16r = l8r*l8r - l8i*l8i,    l16i = 2.f*l8r*l8i;
        float l32r = l16r*l16r - l16i*l16i, l32i = 2.f*l16r*l16i;
        float l48r = l32r*l16r - l32i*l16i, l48i = l32r*l16i + l32i*l16r;
        float p1r[4] = {1.f, lr, l2r, l3r},     p1i[4] = {0.f, li, l2i, l3i};
        float p4r[4] = {1.f, l4r, l8r, l12r},   p4i[4] = {0.f, l4i, l8i, l12i};
        float p16r[4] = {1.f, l16r, l32r, l48r}, p16i[4] = {0.f, l16i, l32i, l48i};
        float wqr = p4r[3 - q], wqi = p4i[3 - q];
        float er = 0.f, ei = 0.f;
#pragma unroll
        for (int r = 0; r < 4; r++) {
            float inr = 0.f, ini = 0.f;
#pragma unroll
            for (int mi = 0; mi < 4; mi++) {
                float v = acc[mi][ni][r];
                inr = fmaf(p16r[3 - mi], v, inr);
                ini = fmaf(p16i[3 - mi], v, ini);
            }
            float wrr = wqr * p1r[3 - r] - wqi * p1i[3 - r];
            float wri = wqr * p1i[3 - r] + wqi * p1r[3 - r];
            er += wrr * inr - wri * ini;
            ei += wrr * ini + wri * inr;
        }
        er += __shfl_xor(er, 16, 64); ei += __shfl_xor(ei, 16, 64);
        er += __shfl_xor(er, 32, 64); ei += __shfl_xor(ei, 32, 64);
        if (q == 0) {
            float2 out; out.x = er; out.y = ei;
            if (ncol < 1024) P1[(long)c_chunk * 1024 + ncol] = out;
            else             P2[(long)c_chunk * 1024 + (ncol - 1024)] = out;
        }
    }

    // ---- epilogue store: restage each 32x128 row-slab through LDS, store ushort8 ----
    const int er4 = (lane >> 4) * 4;
    const int rowg = wm >> 6;
#pragma unroll
    for (int mi = 0; mi < 4; mi++) {
        __syncthreads();
#pragma unroll
        for (int ni = 0; ni < 4; ni++)
#pragma unroll
            for (int r = 0; r < 4; r++)
                smem[(rowg * 16 + er4 + r) * 136 + wn + ni * 16 + ec] = f2b(acc[mi][ni][r]);
        __syncthreads();
#pragma unroll
        for (int h = 0; h < 2; h++) {
            int j = h * 256 + tid;
            int rp = j >> 4;
            int cp = (j & 15) * 8;
            short8 v = *(const short8*)(smem + rp * 136 + cp);
            long grow = m0 + (rp >> 4) * 64 + mi * 16 + (rp & 15);
            *(short8*)(Cout + grow * ldc + n0 + cp) = v;
        }
    }
}

// ---------- apply: Horner carry from E-partials (prev dispatch; no sync) + in-place rescan ----------
__launch_bounds__(256)
__global__ void apply_scan(unsigned short* __restrict__ Hcat,
                           const float* __restrict__ lamb,
                           const float2* __restrict__ Ltab,
                           const float2* __restrict__ P1,
                           const float2* __restrict__ P2) {
    const int c = blockIdx.x;          // chunk of 64 rows
    const int ch = threadIdx.x << 2;   // 4 channels per thread
    float lre[4], lim[4], t64re[4], t64im[4];
#pragma unroll
    for (int i = 0; i < 4; i++) {
        float2 l = Ltab[ch + i];
        lre[i] = l.x; lim[i] = l.y;
        double dnu = exp(-exp((double)lamb[ch + i]));
        double dth = exp((double)lamb[1024 + ch + i]);
        double lr = dnu * cos(dth), li = dnu * sin(dth);
#pragma unroll
        for (int s = 0; s < 6; s++) {  // lambda^64
            double rr = lr * lr - li * li;
            double ii = 2.0 * lr * li;
            lr = rr; li = ii;
        }
        t64re[i] = (float)lr; t64im[i] = (float)li;
    }

    // carry = sum_{j<c} lam64^(c-1-j) * (P1[j] + i*P2[j]),  Horner ascending j
    float cr[4] = {0, 0, 0, 0}, ci[4] = {0, 0, 0, 0};
#pragma unroll 4
    for (int j = 0; j < c; j++) {
        const float2* p1 = P1 + (long)j * 1024 + ch;
        const float2* p2 = P2 + (long)j * 1024 + ch;
#pragma unroll
        for (int i = 0; i < 4; i++) {
            float2 a = p1[i], b = p2[i];
            float er = a.x - b.y;          // Re(P1 + i*P2)
            float ei = a.y + b.x;          // Im
            float nr = fmaf(t64re[i], cr[i], fmaf(-t64im[i], ci[i], er));
            float ni = fmaf(t64re[i], ci[i], fmaf( t64im[i], cr[i], ei));
            cr[i] = nr; ci[i] = ni;
        }
    }

    // rescan chunk seeded with carry; write h bf16 in place
    unsigned short* base = Hcat + (long)c * TCHUNK * LDH + ch;
    float hr[4], hi[4];
#pragma unroll
    for (int i = 0; i < 4; i++) { hr[i] = cr[i]; hi[i] = ci[i]; }
#pragma unroll 4
    for (int t = 0; t < TCHUNK; t++) {
        ushort4 br = *(const ushort4*)(base + (long)t * LDH);
        ushort4 bi = *(const ushort4*)(base + (long)t * LDH + 1024);
        float brf[4] = {b2f(br.x), b2f(br.y), b2f(br.z), b2f(br.w)};
        float bif[4] = {b2f(bi.x), b2f(bi.y), b2f(bi.z), b2f(bi.w)};
#pragma unroll
        for (int i = 0; i < 4; i++) {
            float nr = fmaf(lre[i], hr[i], fmaf(-lim[i], hi[i], brf[i]));
            float ni = fmaf(lre[i], hi[i], fmaf(lim[i], hr[i], bif[i]));
            hr[i] = nr; hi[i] = ni;
        }
        ushort4 orv, oiv;
        orv.x = f2b(hr[0]); orv.y = f2b(hr[1]); orv.z = f2b(hr[2]); orv.w = f2b(hr[3]);
        oiv.x = f2b(hi[0]); oiv.y = f2b(hi[1]); oiv.z = f2b(hi[2]); oiv.w = f2b(hi[3]);
        *(ushort4*)(base + (long)t * LDH) = orv;
        *(ushort4*)(base + (long)t * LDH + 1024) = oiv;
    }
}

// ---------- GEMM2: single-wave 64x128 tile, BK=32, LDS dbuf + vmcnt(12) (R4 best) ----------
__launch_bounds__(64, 2)
__global__ void g2_out_gemm(const unsigned short* __restrict__ A, int lda,
                            const unsigned short* __restrict__ B, int ldb,
                            float* __restrict__ Cout, int ldc, int Ktot,
                            int nbx_shift) {
    __shared__ unsigned short sm[2][6144] __attribute__((aligned(16)));
    const int lane = threadIdx.x;

    const int bid = blockIdx.x;
    const int xcd = bid & 7;
    const int g = bid >> 3;
    const int bx = g & ((1 << nbx_shift) - 1);
    const int by = xcd * 32 + (g >> nbx_shift);
    const long m0 = (long)by * 64;
    const long n0 = (long)bx * 128;

    const unsigned short* Ag = A + (m0 + (lane >> 2)) * lda + (lane & 3) * 8;
    const unsigned short* Bg = B + (n0 + (lane >> 2)) * ldb + (lane & 3) * 8;

    const int fr = lane & 15;
    const int fk = (lane >> 4) * 8;

    float4v acc[4][8] = {};

    auto stage = [&](int b, int k0) {
#pragma unroll
        for (int i = 0; i < 4; i++)
            GLD16(Ag + (long)i * 16 * lda + k0, &sm[b][i * 512]);
#pragma unroll
        for (int j = 0; j < 8; j++)
            GLD16(Bg + (long)j * 16 * ldb + k0, &sm[b][2048 + j * 512]);
    };
    auto compute = [&](int b) {
        short8 af[4], bf8[8];
#pragma unroll
        for (int i = 0; i < 4; i++)
            af[i] = *(const short8*)(&sm[b][(i * 16 + fr) * 32 + fk]);
#pragma unroll
        for (int j = 0; j < 8; j++)
            bf8[j] = *(const short8*)(&sm[b][2048 + (j * 16 + fr) * 32 + fk]);
#pragma unroll
        for (int mi = 0; mi < 4; mi++)
#pragma unroll
            for (int ni = 0; ni < 8; ni++)
                acc[mi][ni] = __builtin_amdgcn_mfma_f32_16x16x32_bf16(af[mi], bf8[ni], acc[mi][ni], 0, 0, 0);
    };

    stage(0, 0);
    int buf = 0;
    int k0 = 0;
    for (; k0 + 32 < Ktot; k0 += 32) {
        stage(buf ^ 1, k0 + 32);
        WAIT_VM12();
        compute(buf);
        buf ^= 1;
    }
    WAIT_VM0();
    compute(buf);

    const int er = (lane >> 4) * 4;
    const int ec = lane & 15;
#pragma unroll
    for (int mi = 0; mi < 4; mi++) {
#pragma unroll
        for (int r = 0; r < 4; r++) {
            long grow = m0 + mi * 16 + er + r;
#pragma unroll
            for (int ni = 0; ni < 8; ni++)
                Cout[grow * ldc + n0 + ni * 16 + ec] = acc[mi][ni][r];
        }
    }
}

// ---------- launch ----------
extern "C" void kernel_launch(void* const* d_in, const int* in_sizes, int n_in,
                              void* d_out, int out_size, void* d_ws, size_t ws_size,
                              hipStream_t stream) {
    const float* x     = (const float*)d_in[0];  // [16384, 512]
    const float* lamb  = (const float*)d_in[1];  // [2, 1024]
    const float* gamma = (const float*)d_in[2];  // [1024]
    const float* B_re  = (const float*)d_in[3];  // [1024, 512]
    const float* B_im  = (const float*)d_in[4];
    const float* C_re  = (const float*)d_in[5];  // [512, 1024]
    const float* C_im  = (const float*)d_in[6];
    const float* Dm    = (const float*)d_in[7];  // [512, 512]

    char* ws = (char*)d_ws;
    unsigned short* Hcat = (unsigned short*)ws;                        // 16384*2560*2 = 83886080
    float2* Ltab = (float2*)(ws + 83886080);                           // 1024*8 = 8192
    float2* P1   = (float2*)(ws + 83886080 + 8192);                    // 256*1024*8 = 2097152
    float2* P2   = P1 + (long)NCHUNK * 1024;                           // 2097152
    unsigned short* Bcat = (unsigned short*)((char*)P2 + 2097152);     // 2048*512*2 = 2097152
    unsigned short* CW   = Bcat + (long)2048 * 512;                    // 512*2560*2 = 2621440

    prep_all<<<10496, 256, 0, stream>>>(x, B_re, B_im, gamma, C_re, C_im, Dm, lamb,
                                        Hcat, Bcat, CW, Ltab);
    // Bu = x_bf16 @ Bcat^T -> Hcat cols [0,2048) + E-partials.  grid 16x128 = 2048 blocks.
    g1_bu_gemm<<<2048, 256, 0, stream>>>(Hcat + 2048, LDH, Bcat, 512, Hcat, LDH, 512,
                                         Ltab, P1, P2);
    // carry (Horner over E-partials) + in-place rescan, one dispatch, no cross-block sync
    apply_scan<<<NCHUNK, 256, 0, stream>>>(Hcat, lamb, Ltab, P1, P2);
    // y = Hcat @ CW^T -> d_out f32.  grid 256(by) x 4(bx) = 1024 single-wave blocks.
    g2_out_gemm<<<1024, 64, 0, stream>>>(Hcat, LDH, CW, 2560, (float*)d_out, 512, 2560,
                                         /*nbx_shift=*/2);
}